// Round 1
// baseline (1048.907 us; speedup 1.0000x reference)
//
#include <hip/hip_runtime.h>

#define N_NODES 50000
#define N_EDGES 800000
#define N_GRAPHS 1000
#define NODE_DIMC 128
#define HDIM 256
#define NLAYERS 4
#define NPROPS 3
#define BN_EPSF 1e-5f
#define NBLK 196   // ceil(N_NODES/256)

__device__ __forceinline__ float4 ld4(const float* p){ return *reinterpret_cast<const float4*>(p); }
__device__ __forceinline__ void st4(float* p, float4 v){ *reinterpret_cast<float4*>(p) = v; }

// ---------------- CSR build ----------------
__global__ void k_count(const int* __restrict__ ei, int* __restrict__ cnt){
  int e = blockIdx.x*256 + threadIdx.x;
  if (e < N_EDGES) atomicAdd(&cnt[ei[N_EDGES + e]], 1);
}

__global__ void k_scan1(const int* __restrict__ cnt, int* __restrict__ rowp, int* __restrict__ part){
  __shared__ int s[256];
  int t = threadIdx.x;
  int i = blockIdx.x*256 + t;
  int v = (i < N_NODES) ? cnt[i] : 0;
  s[t] = v;
  __syncthreads();
  #pragma unroll
  for (int off=1; off<256; off<<=1){
    int x = s[t];
    int y = (t >= off) ? s[t-off] : 0;
    __syncthreads();
    s[t] = x + y;
    __syncthreads();
  }
  if (i < N_NODES) rowp[i+1] = s[t];
  if (t == 255) part[blockIdx.x] = s[255];
}

__global__ void k_scan2(int* __restrict__ part){
  __shared__ int s[256];
  int t = threadIdx.x;
  int v = (t < NBLK) ? part[t] : 0;
  s[t] = v;
  __syncthreads();
  #pragma unroll
  for (int off=1; off<256; off<<=1){
    int x = s[t];
    int y = (t >= off) ? s[t-off] : 0;
    __syncthreads();
    s[t] = x + y;
    __syncthreads();
  }
  if (t < NBLK) part[t] = s[t] - v;   // exclusive offsets
}

__global__ void k_scan3(const int* __restrict__ cnt, int* __restrict__ rowp,
                        const int* __restrict__ part, float* __restrict__ dinv){
  int i = blockIdx.x*256 + threadIdx.x;
  if (i < N_NODES){
    rowp[i+1] += part[blockIdx.x];
    dinv[i] = rsqrtf(1.0f + (float)cnt[i]);
  }
  if (i == 0) rowp[0] = 0;
}

__global__ void k_fill(const int* __restrict__ ei, const int* __restrict__ rowp, int* __restrict__ fill,
                       const float* __restrict__ dinv, int* __restrict__ csrs, float* __restrict__ csrw){
  int e = blockIdx.x*256 + threadIdx.x;
  if (e >= N_EDGES) return;
  int sr = ei[e];
  int ds = ei[N_EDGES + e];
  int pos = rowp[ds] + atomicAdd(&fill[ds], 1);
  csrs[pos] = sr;
  csrw[pos] = dinv[sr] * dinv[ds];
}

// ---------------- fp32 tiled GEMM: out[r,c] = A[r,:K] @ W[:K,256] (+bias)(+relu) ----------------
// BM=64, BN=64, BK=32; 256 threads, 4x4 per thread.
template<int K, bool RELU, bool HASBIAS>
__global__ __launch_bounds__(256) void k_gemm(const float* __restrict__ A, const float* __restrict__ W,
                                              const float* __restrict__ bias, float* __restrict__ out,
                                              int nrows){
  __shared__ float As[32][68];  // [k][row], padded stride 68 (16B-aligned float4 rows)
  __shared__ float Ws[32][68];  // [k][col]
  const int t = threadIdx.x;
  const int row0 = blockIdx.x * 64;
  const int col0 = blockIdx.y * 64;
  const int ty = t >> 4, tx = t & 15;
  const int r = ty * 4, c = tx * 4;

  float acc[4][4];
  #pragma unroll
  for (int i=0;i<4;i++)
    #pragma unroll
    for (int j=0;j<4;j++) acc[i][j] = 0.f;

  for (int k0 = 0; k0 < K; k0 += 32){
    // stage A tile (64 rows x 32 k), transposed into As[k][row]
    #pragma unroll
    for (int i=0;i<2;i++){
      int f = t + i*256;          // float4 index 0..511
      int ar = f >> 3;            // row in tile
      int ak = (f & 7) * 4;       // k in tile
      float4 v = make_float4(0.f,0.f,0.f,0.f);
      int gr = row0 + ar;
      if (gr < nrows) v = ld4(A + (size_t)gr*K + k0 + ak);
      As[ak+0][ar] = v.x; As[ak+1][ar] = v.y; As[ak+2][ar] = v.z; As[ak+3][ar] = v.w;
    }
    // stage W tile (32 k x 64 cols)
    #pragma unroll
    for (int i=0;i<2;i++){
      int f = t + i*256;
      int wk = f >> 4;            // k
      int wc = (f & 15) * 4;      // col
      float4 v = ld4(W + (size_t)(k0+wk)*HDIM + col0 + wc);
      st4(&Ws[wk][wc], v);
    }
    __syncthreads();
    #pragma unroll
    for (int k=0;k<32;k++){
      float4 a = ld4(&As[k][r]);
      float4 b = ld4(&Ws[k][c]);
      acc[0][0] += a.x*b.x; acc[0][1] += a.x*b.y; acc[0][2] += a.x*b.z; acc[0][3] += a.x*b.w;
      acc[1][0] += a.y*b.x; acc[1][1] += a.y*b.y; acc[1][2] += a.y*b.z; acc[1][3] += a.y*b.w;
      acc[2][0] += a.z*b.x; acc[2][1] += a.z*b.y; acc[2][2] += a.z*b.z; acc[2][3] += a.z*b.w;
      acc[3][0] += a.w*b.x; acc[3][1] += a.w*b.y; acc[3][2] += a.w*b.z; acc[3][3] += a.w*b.w;
    }
    __syncthreads();
  }

  float4 bv = make_float4(0.f,0.f,0.f,0.f);
  if (HASBIAS) bv = ld4(bias + col0 + c);
  #pragma unroll
  for (int i=0;i<4;i++){
    int gr = row0 + r + i;
    if (gr < nrows){
      float4 o;
      o.x = acc[i][0] + bv.x; o.y = acc[i][1] + bv.y; o.z = acc[i][2] + bv.z; o.w = acc[i][3] + bv.w;
      if (RELU){ o.x = fmaxf(o.x,0.f); o.y = fmaxf(o.y,0.f); o.z = fmaxf(o.z,0.f); o.w = fmaxf(o.w,0.f); }
      st4(out + (size_t)gr*HDIM + col0 + c, o);
    }
  }
}

// ---------------- fused aggregation + bias + BN + relu + residual (in-place h) ----------------
// one wave (64 lanes) per node; lane owns 4 channels.
__global__ __launch_bounds__(256) void k_agg(const float* __restrict__ m, const int* __restrict__ rowp,
                                             const int* __restrict__ csrs, const float* __restrict__ csrw,
                                             const float* __restrict__ dinv,
                                             const float* __restrict__ bvec, const float* __restrict__ gam,
                                             const float* __restrict__ bet, const float* __restrict__ mu,
                                             const float* __restrict__ var, float* __restrict__ h){
  int node = blockIdx.x*4 + (threadIdx.x >> 6);
  if (node >= N_NODES) return;
  int lane = threadIdx.x & 63;
  int c = lane * 4;

  float dn = dinv[node];
  float sn = dn * dn;
  float4 ms = ld4(m + (size_t)node*HDIM + c);
  float4 acc;
  acc.x = ms.x*sn; acc.y = ms.y*sn; acc.z = ms.z*sn; acc.w = ms.w*sn;

  int s = rowp[node], e = rowp[node+1];
  int i = s;
  for (; i + 1 < e; i += 2){
    int s0 = csrs[i],   s1 = csrs[i+1];
    float w0 = csrw[i], w1 = csrw[i+1];
    float4 m0 = ld4(m + (size_t)s0*HDIM + c);
    float4 m1 = ld4(m + (size_t)s1*HDIM + c);
    acc.x += w0*m0.x + w1*m1.x;
    acc.y += w0*m0.y + w1*m1.y;
    acc.z += w0*m0.z + w1*m1.z;
    acc.w += w0*m0.w + w1*m1.w;
  }
  if (i < e){
    int s0 = csrs[i]; float w0 = csrw[i];
    float4 m0 = ld4(m + (size_t)s0*HDIM + c);
    acc.x += w0*m0.x; acc.y += w0*m0.y; acc.z += w0*m0.z; acc.w += w0*m0.w;
  }

  float4 b4 = ld4(bvec + c);
  float4 g4 = ld4(gam + c);
  float4 t4 = ld4(bet + c);
  float4 u4 = ld4(mu + c);
  float4 v4 = ld4(var + c);
  float4 hold = ld4(h + (size_t)node*HDIM + c);

  float4 o;
  o.x = fmaxf((acc.x + b4.x - u4.x) * rsqrtf(v4.x + BN_EPSF) * g4.x + t4.x, 0.f) + hold.x;
  o.y = fmaxf((acc.y + b4.y - u4.y) * rsqrtf(v4.y + BN_EPSF) * g4.y + t4.y, 0.f) + hold.y;
  o.z = fmaxf((acc.z + b4.z - u4.z) * rsqrtf(v4.z + BN_EPSF) * g4.z + t4.z, 0.f) + hold.z;
  o.w = fmaxf((acc.w + b4.w - u4.w) * rsqrtf(v4.w + BN_EPSF) * g4.w + t4.w, 0.f) + hold.w;
  st4(h + (size_t)node*HDIM + c, o);
}

// ---------------- global mean pool (batch_idx sorted) ----------------
__device__ __forceinline__ int lbound(const int* __restrict__ a, int n, int key){
  int lo = 0, hi = n;
  while (lo < hi){ int mid = (lo + hi) >> 1; if (a[mid] < key) lo = mid + 1; else hi = mid; }
  return lo;
}

__global__ __launch_bounds__(256) void k_pool(const float* __restrict__ h, const int* __restrict__ batch,
                                              float* __restrict__ g){
  int gi = blockIdx.x;
  int lo = lbound(batch, N_NODES, gi);
  int hi = lbound(batch, N_NODES, gi + 1);
  float sum = 0.f;
  for (int n = lo; n < hi; ++n) sum += h[(size_t)n*HDIM + threadIdx.x];
  float inv = 1.0f / fmaxf((float)(hi - lo), 1.0f);
  g[(size_t)gi*HDIM + threadIdx.x] = sum * inv;
}

// ---------------- fused 3-layer property heads ----------------
__global__ __launch_bounds__(128) void k_heads(const float* __restrict__ g,
                                               const float* __restrict__ W1, const float* __restrict__ b1,
                                               const float* __restrict__ W2, const float* __restrict__ b2,
                                               const float* __restrict__ W3, const float* __restrict__ b3,
                                               float* __restrict__ out){
  int gi = blockIdx.x, p = blockIdx.y;
  __shared__ float gs[HDIM];
  __shared__ float z1[128];
  int t = threadIdx.x;
  gs[t]       = g[(size_t)gi*HDIM + t];
  gs[t + 128] = g[(size_t)gi*HDIM + t + 128];
  __syncthreads();

  const float* w1 = W1 + (size_t)p*HDIM*128;
  float a = 0.f;
  #pragma unroll 4
  for (int i=0;i<HDIM;i++) a += gs[i] * w1[(size_t)i*128 + t];
  z1[t] = fmaxf(a + b1[p*128 + t], 0.f);
  __syncthreads();

  if (t < 64){
    const float* w2 = W2 + (size_t)p*128*64;
    float a2 = 0.f;
    #pragma unroll 4
    for (int i=0;i<128;i++) a2 += z1[i] * w2[(size_t)i*64 + t];
    float z2 = fmaxf(a2 + b2[p*64 + t], 0.f);
    float v = z2 * W3[p*64 + t];
    #pragma unroll
    for (int off=32; off>0; off>>=1) v += __shfl_down(v, off, 64);
    if (t == 0) out[gi*NPROPS + p] = v + b3[p];
  }
}

// ---------------- launch ----------------
extern "C" void kernel_launch(void* const* d_in, const int* in_sizes, int n_in,
                              void* d_out, int out_size, void* d_ws, size_t ws_size,
                              hipStream_t stream){
  const float* x     = (const float*)d_in[0];
  const int*   ei    = (const int*)  d_in[1];
  const int*   batch = (const int*)  d_in[2];
  const float* embW  = (const float*)d_in[3];
  const float* embb  = (const float*)d_in[4];
  const float* gcnW  = (const float*)d_in[5];
  const float* gcnb  = (const float*)d_in[6];
  const float* bng   = (const float*)d_in[7];
  const float* bnb   = (const float*)d_in[8];
  const float* bnm   = (const float*)d_in[9];
  const float* bnv   = (const float*)d_in[10];
  const float* h1W   = (const float*)d_in[11];
  const float* h1b   = (const float*)d_in[12];
  const float* h2W   = (const float*)d_in[13];
  const float* h2b   = (const float*)d_in[14];
  const float* h3W   = (const float*)d_in[15];
  const float* h3b   = (const float*)d_in[16];
  float* out = (float*)d_out;

  char* w = (char*)d_ws;
  auto alloc = [&](size_t bytes)->char*{ char* p = w; w += (bytes + 255) & ~(size_t)255; return p; };
  float* h    = (float*)alloc((size_t)N_NODES*HDIM*4);
  float* m    = (float*)alloc((size_t)N_NODES*HDIM*4);
  int*   cnt  = (int*)  alloc((size_t)N_NODES*4);
  int*   fill = (int*)  alloc((size_t)N_NODES*4);
  int*   rowp = (int*)  alloc((size_t)(N_NODES+1)*4);
  float* dinv = (float*)alloc((size_t)N_NODES*4);
  int*   csrs = (int*)  alloc((size_t)N_EDGES*4);
  float* csrw = (float*)alloc((size_t)N_EDGES*4);
  int*   part = (int*)  alloc(1024);
  float* gp   = (float*)alloc((size_t)N_GRAPHS*HDIM*4);

  hipMemsetAsync(cnt, 0, (size_t)N_NODES*4, stream);
  hipMemsetAsync(fill, 0, (size_t)N_NODES*4, stream);

  const int EB = (N_EDGES + 255)/256;
  k_count<<<EB,256,0,stream>>>(ei, cnt);
  k_scan1<<<NBLK,256,0,stream>>>(cnt, rowp, part);
  k_scan2<<<1,256,0,stream>>>(part);
  k_scan3<<<NBLK,256,0,stream>>>(cnt, rowp, part, dinv);
  k_fill<<<EB,256,0,stream>>>(ei, rowp, fill, dinv, csrs, csrw);

  const int RB = (N_NODES + 63)/64;
  k_gemm<NODE_DIMC, true, true><<<dim3(RB,4),256,0,stream>>>(x, embW, embb, h, N_NODES);

  for (int l = 0; l < NLAYERS; ++l){
    k_gemm<HDIM, false, false><<<dim3(RB,4),256,0,stream>>>(h, gcnW + (size_t)l*HDIM*HDIM, nullptr, m, N_NODES);
    k_agg<<<(N_NODES+3)/4,256,0,stream>>>(m, rowp, csrs, csrw, dinv,
                                          gcnb + l*HDIM, bng + l*HDIM, bnb + l*HDIM,
                                          bnm + l*HDIM, bnv + l*HDIM, h);
  }

  k_pool<<<N_GRAPHS,256,0,stream>>>(h, batch, gp);
  k_heads<<<dim3(N_GRAPHS,NPROPS),128,0,stream>>>(gp, h1W, h1b, h2W, h2b, h3W, h3b, out);
}

// Round 2
// 584.351 us; speedup vs baseline: 1.7950x; 1.7950x over previous
//
#include <hip/hip_runtime.h>

#define N_NODES 50000
#define N_EDGES 800000
#define N_GRAPHS 1000
#define NODE_DIMC 128
#define HDIM 256
#define NLAYERS 4
#define NPROPS 3
#define BN_EPSF 1e-5f
#define NBLK 196   // ceil(N_NODES/256)

typedef __attribute__((ext_vector_type(4))) float f32x4;
typedef __attribute__((ext_vector_type(8))) short short8;

__device__ __forceinline__ float4 ld4(const float* p){ return *reinterpret_cast<const float4*>(p); }
__device__ __forceinline__ void st4(float* p, float4 v){ *reinterpret_cast<float4*>(p) = v; }
__device__ __forceinline__ unsigned short f2bf(float f){
  unsigned u = __float_as_uint(f);
  return (unsigned short)((u + 0x7FFFu + ((u >> 16) & 1u)) >> 16);
}
__device__ __forceinline__ float bf2f(unsigned short s){ return __uint_as_float(((unsigned)s) << 16); }

// ---------------- CSR build ----------------
__global__ void k_count(const int* __restrict__ ei, int* __restrict__ cnt){
  int e = blockIdx.x*256 + threadIdx.x;
  if (e < N_EDGES) atomicAdd(&cnt[ei[N_EDGES + e]], 1);
}

__global__ void k_scan1(const int* __restrict__ cnt, int* __restrict__ rowp, int* __restrict__ part){
  __shared__ int s[256];
  int t = threadIdx.x;
  int i = blockIdx.x*256 + t;
  int v = (i < N_NODES) ? cnt[i] : 0;
  s[t] = v;
  __syncthreads();
  #pragma unroll
  for (int off=1; off<256; off<<=1){
    int x = s[t];
    int y = (t >= off) ? s[t-off] : 0;
    __syncthreads();
    s[t] = x + y;
    __syncthreads();
  }
  if (i < N_NODES) rowp[i+1] = s[t];
  if (t == 255) part[blockIdx.x] = s[255];
}

__global__ void k_scan2(int* __restrict__ part){
  __shared__ int s[256];
  int t = threadIdx.x;
  int v = (t < NBLK) ? part[t] : 0;
  s[t] = v;
  __syncthreads();
  #pragma unroll
  for (int off=1; off<256; off<<=1){
    int x = s[t];
    int y = (t >= off) ? s[t-off] : 0;
    __syncthreads();
    s[t] = x + y;
    __syncthreads();
  }
  if (t < NBLK) part[t] = s[t] - v;   // exclusive offsets
}

__global__ void k_scan3(const int* __restrict__ cnt, int* __restrict__ rowp,
                        const int* __restrict__ part, float* __restrict__ dinv){
  int i = blockIdx.x*256 + threadIdx.x;
  if (i < N_NODES){
    rowp[i+1] += part[blockIdx.x];
    dinv[i] = rsqrtf(1.0f + (float)cnt[i]);
  }
  if (i == 0) rowp[0] = 0;
}

__global__ void k_fill(const int* __restrict__ ei, const int* __restrict__ rowp, int* __restrict__ fill,
                       const float* __restrict__ dinv, int* __restrict__ csrs, float* __restrict__ csrw){
  int e = blockIdx.x*256 + threadIdx.x;
  if (e >= N_EDGES) return;
  int sr = ei[e];
  int ds = ei[N_EDGES + e];
  int pos = rowp[ds] + atomicAdd(&fill[ds], 1);
  csrs[pos] = sr;
  csrw[pos] = dinv[sr] * dinv[ds];
}

// ---------------- weight prep: Wt[c][k] = bf16(W[k][c]) ----------------
__global__ void k_wt(const float* __restrict__ W, unsigned short* __restrict__ Wt, int Kd, int Cd){
  int idx = blockIdx.x*256 + threadIdx.x;
  if (idx >= Kd*Cd) return;
  int c = idx / Kd, k = idx - c*Kd;
  Wt[idx] = f2bf(W[(size_t)k*Cd + c]);
}

// ---------------- f32 -> bf16 convert (n multiple of 4) ----------------
__global__ void k_cvt(const float* __restrict__ in, unsigned short* __restrict__ out, int n4){
  int i = blockIdx.x*256 + threadIdx.x;
  if (i >= n4) return;
  float4 v = ld4(in + (size_t)i*4);
  ushort4 o;
  o.x = f2bf(v.x); o.y = f2bf(v.y); o.z = f2bf(v.z); o.w = f2bf(v.w);
  *reinterpret_cast<ushort4*>(out + (size_t)i*4) = o;
}

// ---------------- bf16 MFMA GEMM: 128x128 tile, BK=64, 4 waves (2x2), 64x64 per wave ----------------
// out[r,c] = A[r,:K] @ Wt[c,:K]^T  (Wt is pre-transposed: Wt[c][k] = W[k][c])
// EMB=true: apply bias+relu, write f32 h and bf16 h. EMB=false: write bf16 m only.
template<int K, bool EMB>
__global__ __launch_bounds__(256) void k_mgemm(const unsigned short* __restrict__ A,
                                               const unsigned short* __restrict__ Wt,
                                               const float* __restrict__ bias,
                                               unsigned short* __restrict__ mout,
                                               float* __restrict__ hf,
                                               unsigned short* __restrict__ hb,
                                               int nrows){
  __shared__ unsigned short As[128][72];   // [row][k], stride 144B -> conflict-free-ish
  __shared__ unsigned short Bs[128][72];   // [col][k]
  const int t = threadIdx.x;
  const int lane = t & 63;
  const int wid = t >> 6;
  const int wm = wid >> 1, wn = wid & 1;
  const int row0 = blockIdx.x * 128;
  const int col0 = blockIdx.y * 128;

  f32x4 acc[4][4];
  #pragma unroll
  for (int i=0;i<4;i++)
    #pragma unroll
    for (int j=0;j<4;j++) acc[i][j] = (f32x4){0.f,0.f,0.f,0.f};

  for (int k0 = 0; k0 < K; k0 += 64){
    // stage A: 128 rows x 64 k bf16 = 1024 chunks of 16B
    #pragma unroll
    for (int i=0;i<4;i++){
      int chunk = t + i*256;
      int row = chunk >> 3;
      int kc = (chunk & 7) * 8;
      int gr = row0 + row;
      int4 v = make_int4(0,0,0,0);
      if (gr < nrows) v = *reinterpret_cast<const int4*>(A + (size_t)gr*K + k0 + kc);
      *reinterpret_cast<int4*>(&As[row][kc]) = v;
    }
    // stage B: 128 cols x 64 k
    #pragma unroll
    for (int i=0;i<4;i++){
      int chunk = t + i*256;
      int col = chunk >> 3;
      int kc = (chunk & 7) * 8;
      int4 v = *reinterpret_cast<const int4*>(Wt + (size_t)(col0+col)*K + k0 + kc);
      *reinterpret_cast<int4*>(&Bs[col][kc]) = v;
    }
    __syncthreads();
    #pragma unroll
    for (int kk=0; kk<64; kk+=32){
      const int kofs = kk + (lane >> 4) * 8;
      short8 af[4], bfv[4];
      #pragma unroll
      for (int mi=0;mi<4;mi++)
        af[mi] = *reinterpret_cast<const short8*>(&As[wm*64 + mi*16 + (lane & 15)][kofs]);
      #pragma unroll
      for (int ni=0;ni<4;ni++)
        bfv[ni] = *reinterpret_cast<const short8*>(&Bs[wn*64 + ni*16 + (lane & 15)][kofs]);
      #pragma unroll
      for (int mi=0;mi<4;mi++)
        #pragma unroll
        for (int ni=0;ni<4;ni++)
          acc[mi][ni] = __builtin_amdgcn_mfma_f32_16x16x32_bf16(af[mi], bfv[ni], acc[mi][ni], 0, 0, 0);
    }
    __syncthreads();
  }

  const int crow = row0 + wm*64;
  const int ccol = col0 + wn*64 + (lane & 15);
  #pragma unroll
  for (int mi=0;mi<4;mi++){
    #pragma unroll
    for (int j=0;j<4;j++){
      int gr = crow + mi*16 + (lane >> 4)*4 + j;
      if (gr < nrows){
        #pragma unroll
        for (int ni=0;ni<4;ni++){
          float v = acc[mi][ni][j];
          int gc = ccol + ni*16;
          if (EMB){
            v = fmaxf(v + bias[gc], 0.f);
            hf[(size_t)gr*HDIM + gc] = v;
            hb[(size_t)gr*HDIM + gc] = f2bf(v);
          } else {
            mout[(size_t)gr*HDIM + gc] = f2bf(v);
          }
        }
      }
    }
  }
}

// ---------------- fused aggregation (bf16 gather) + bias + BN + relu + residual ----------------
// one wave per node; lane owns 4 channels. writes h (f32, in place) and hb (bf16 mirror).
__global__ __launch_bounds__(256) void k_agg(const unsigned short* __restrict__ m, const int* __restrict__ rowp,
                                             const int* __restrict__ csrs, const float* __restrict__ csrw,
                                             const float* __restrict__ dinv,
                                             const float* __restrict__ bvec, const float* __restrict__ gam,
                                             const float* __restrict__ bet, const float* __restrict__ mu,
                                             const float* __restrict__ var, float* __restrict__ h,
                                             unsigned short* __restrict__ hb){
  int node = blockIdx.x*4 + (threadIdx.x >> 6);
  if (node >= N_NODES) return;
  int lane = threadIdx.x & 63;
  int c = lane * 4;

  float dn = dinv[node];
  float sn = dn * dn;
  ushort4 ms = *reinterpret_cast<const ushort4*>(m + (size_t)node*HDIM + c);
  float ax = bf2f(ms.x)*sn, ay = bf2f(ms.y)*sn, az = bf2f(ms.z)*sn, aw = bf2f(ms.w)*sn;

  int s = rowp[node], e = rowp[node+1];
  int i = s;
  for (; i + 1 < e; i += 2){
    int s0 = csrs[i],   s1 = csrs[i+1];
    float w0 = csrw[i], w1 = csrw[i+1];
    ushort4 m0 = *reinterpret_cast<const ushort4*>(m + (size_t)s0*HDIM + c);
    ushort4 m1 = *reinterpret_cast<const ushort4*>(m + (size_t)s1*HDIM + c);
    ax += w0*bf2f(m0.x) + w1*bf2f(m1.x);
    ay += w0*bf2f(m0.y) + w1*bf2f(m1.y);
    az += w0*bf2f(m0.z) + w1*bf2f(m1.z);
    aw += w0*bf2f(m0.w) + w1*bf2f(m1.w);
  }
  if (i < e){
    int s0 = csrs[i]; float w0 = csrw[i];
    ushort4 m0 = *reinterpret_cast<const ushort4*>(m + (size_t)s0*HDIM + c);
    ax += w0*bf2f(m0.x); ay += w0*bf2f(m0.y); az += w0*bf2f(m0.z); aw += w0*bf2f(m0.w);
  }

  float4 b4 = ld4(bvec + c);
  float4 g4 = ld4(gam + c);
  float4 t4 = ld4(bet + c);
  float4 u4 = ld4(mu + c);
  float4 v4 = ld4(var + c);
  float4 hold = ld4(h + (size_t)node*HDIM + c);

  float4 o;
  o.x = fmaxf((ax + b4.x - u4.x) * rsqrtf(v4.x + BN_EPSF) * g4.x + t4.x, 0.f) + hold.x;
  o.y = fmaxf((ay + b4.y - u4.y) * rsqrtf(v4.y + BN_EPSF) * g4.y + t4.y, 0.f) + hold.y;
  o.z = fmaxf((az + b4.z - u4.z) * rsqrtf(v4.z + BN_EPSF) * g4.z + t4.z, 0.f) + hold.z;
  o.w = fmaxf((aw + b4.w - u4.w) * rsqrtf(v4.w + BN_EPSF) * g4.w + t4.w, 0.f) + hold.w;
  st4(h + (size_t)node*HDIM + c, o);
  ushort4 ob;
  ob.x = f2bf(o.x); ob.y = f2bf(o.y); ob.z = f2bf(o.z); ob.w = f2bf(o.w);
  *reinterpret_cast<ushort4*>(hb + (size_t)node*HDIM + c) = ob;
}

// ---------------- global mean pool (batch_idx sorted) ----------------
__device__ __forceinline__ int lbound(const int* __restrict__ a, int n, int key){
  int lo = 0, hi = n;
  while (lo < hi){ int mid = (lo + hi) >> 1; if (a[mid] < key) lo = mid + 1; else hi = mid; }
  return lo;
}

__global__ __launch_bounds__(256) void k_pool(const float* __restrict__ h, const int* __restrict__ batch,
                                              float* __restrict__ g){
  int gi = blockIdx.x;
  int lo = lbound(batch, N_NODES, gi);
  int hi = lbound(batch, N_NODES, gi + 1);
  float sum = 0.f;
  for (int n = lo; n < hi; ++n) sum += h[(size_t)n*HDIM + threadIdx.x];
  float inv = 1.0f / fmaxf((float)(hi - lo), 1.0f);
  g[(size_t)gi*HDIM + threadIdx.x] = sum * inv;
}

// ---------------- fused 3-layer property heads ----------------
__global__ __launch_bounds__(128) void k_heads(const float* __restrict__ g,
                                               const float* __restrict__ W1, const float* __restrict__ b1,
                                               const float* __restrict__ W2, const float* __restrict__ b2,
                                               const float* __restrict__ W3, const float* __restrict__ b3,
                                               float* __restrict__ out){
  int gi = blockIdx.x, p = blockIdx.y;
  __shared__ float gs[HDIM];
  __shared__ float z1[128];
  int t = threadIdx.x;
  gs[t]       = g[(size_t)gi*HDIM + t];
  gs[t + 128] = g[(size_t)gi*HDIM + t + 128];
  __syncthreads();

  const float* w1 = W1 + (size_t)p*HDIM*128;
  float a = 0.f;
  #pragma unroll 4
  for (int i=0;i<HDIM;i++) a += gs[i] * w1[(size_t)i*128 + t];
  z1[t] = fmaxf(a + b1[p*128 + t], 0.f);
  __syncthreads();

  if (t < 64){
    const float* w2 = W2 + (size_t)p*128*64;
    float a2 = 0.f;
    #pragma unroll 4
    for (int i=0;i<128;i++) a2 += z1[i] * w2[(size_t)i*64 + t];
    float z2 = fmaxf(a2 + b2[p*64 + t], 0.f);
    float v = z2 * W3[p*64 + t];
    #pragma unroll
    for (int off=32; off>0; off>>=1) v += __shfl_down(v, off, 64);
    if (t == 0) out[gi*NPROPS + p] = v + b3[p];
  }
}

// ---------------- launch ----------------
extern "C" void kernel_launch(void* const* d_in, const int* in_sizes, int n_in,
                              void* d_out, int out_size, void* d_ws, size_t ws_size,
                              hipStream_t stream){
  const float* x     = (const float*)d_in[0];
  const int*   ei    = (const int*)  d_in[1];
  const int*   batch = (const int*)  d_in[2];
  const float* embW  = (const float*)d_in[3];
  const float* embb  = (const float*)d_in[4];
  const float* gcnW  = (const float*)d_in[5];
  const float* gcnb  = (const float*)d_in[6];
  const float* bng   = (const float*)d_in[7];
  const float* bnb   = (const float*)d_in[8];
  const float* bnm   = (const float*)d_in[9];
  const float* bnv   = (const float*)d_in[10];
  const float* h1W   = (const float*)d_in[11];
  const float* h1b   = (const float*)d_in[12];
  const float* h2W   = (const float*)d_in[13];
  const float* h2b   = (const float*)d_in[14];
  const float* h3W   = (const float*)d_in[15];
  const float* h3b   = (const float*)d_in[16];
  float* out = (float*)d_out;

  char* w = (char*)d_ws;
  auto alloc = [&](size_t bytes)->char*{ char* p = w; w += (bytes + 255) & ~(size_t)255; return p; };
  float*          h    = (float*)         alloc((size_t)N_NODES*HDIM*4);   // f32 h (residual chain)
  unsigned short* hb   = (unsigned short*)alloc((size_t)N_NODES*HDIM*2);   // bf16 mirror of h (GEMM A input)
  unsigned short* m    = (unsigned short*)alloc((size_t)N_NODES*HDIM*2);   // bf16 messages; also reused as x_bf16
  int*   cnt  = (int*)  alloc((size_t)N_NODES*4);
  int*   fill = (int*)  alloc((size_t)N_NODES*4);
  int*   rowp = (int*)  alloc((size_t)(N_NODES+1)*4);
  float* dinv = (float*)alloc((size_t)N_NODES*4);
  int*   csrs = (int*)  alloc((size_t)N_EDGES*4);
  float* csrw = (float*)alloc((size_t)N_EDGES*4);
  int*   part = (int*)  alloc(1024);
  float* gp   = (float*)alloc((size_t)N_GRAPHS*HDIM*4);
  unsigned short* embWt = (unsigned short*)alloc((size_t)NODE_DIMC*HDIM*2);          // [256 c][128 k]
  unsigned short* gcnWt = (unsigned short*)alloc((size_t)NLAYERS*HDIM*HDIM*2);       // [l][256 c][256 k]

  hipMemsetAsync(cnt, 0, (size_t)N_NODES*4, stream);
  hipMemsetAsync(fill, 0, (size_t)N_NODES*4, stream);

  const int EB = (N_EDGES + 255)/256;
  k_count<<<EB,256,0,stream>>>(ei, cnt);
  k_scan1<<<NBLK,256,0,stream>>>(cnt, rowp, part);
  k_scan2<<<1,256,0,stream>>>(part);
  k_scan3<<<NBLK,256,0,stream>>>(cnt, rowp, part, dinv);
  k_fill<<<EB,256,0,stream>>>(ei, rowp, fill, dinv, csrs, csrw);

  // weight prep
  k_wt<<<(NODE_DIMC*HDIM + 255)/256,256,0,stream>>>(embW, embWt, NODE_DIMC, HDIM);
  for (int l = 0; l < NLAYERS; ++l)
    k_wt<<<(HDIM*HDIM + 255)/256,256,0,stream>>>(gcnW + (size_t)l*HDIM*HDIM, gcnWt + (size_t)l*HDIM*HDIM, HDIM, HDIM);

  // x -> bf16 (into m buffer, consumed by emb GEMM before m is written)
  unsigned short* xb = m;
  k_cvt<<<(N_NODES*NODE_DIMC/4 + 255)/256,256,0,stream>>>(x, xb, N_NODES*NODE_DIMC/4);

  const int RB = (N_NODES + 127)/128;
  k_mgemm<NODE_DIMC, true><<<dim3(RB,2),256,0,stream>>>(xb, embWt, embb, nullptr, h, hb, N_NODES);

  for (int l = 0; l < NLAYERS; ++l){
    k_mgemm<HDIM, false><<<dim3(RB,2),256,0,stream>>>(hb, gcnWt + (size_t)l*HDIM*HDIM, nullptr, m, nullptr, nullptr, N_NODES);
    k_agg<<<(N_NODES+3)/4,256,0,stream>>>(m, rowp, csrs, csrw, dinv,
                                          gcnb + l*HDIM, bng + l*HDIM, bnb + l*HDIM,
                                          bnm + l*HDIM, bnv + l*HDIM, h, hb);
  }

  k_pool<<<N_GRAPHS,256,0,stream>>>(h, batch, gp);
  k_heads<<<dim3(N_GRAPHS,NPROPS),128,0,stream>>>(gp, h1W, h1b, h2W, h2b, h3W, h3b, out);
}

// Round 3
// 559.287 us; speedup vs baseline: 1.8754x; 1.0448x over previous
//
#include <hip/hip_runtime.h>

#define N_NODES 50000
#define N_EDGES 800000
#define N_GRAPHS 1000
#define NODE_DIMC 128
#define HDIM 256
#define NLAYERS 4
#define NPROPS 3
#define BN_EPSF 1e-5f
#define NBLK 196   // ceil(N_NODES/256)
#define GB 8       // graphs per head-block

typedef __attribute__((ext_vector_type(4))) float f32x4;
typedef __attribute__((ext_vector_type(8))) short short8;
typedef __attribute__((ext_vector_type(8))) unsigned short u16x8;

__device__ __forceinline__ float4 ld4(const float* p){ return *reinterpret_cast<const float4*>(p); }
__device__ __forceinline__ void st4(float* p, float4 v){ *reinterpret_cast<float4*>(p) = v; }
__device__ __forceinline__ unsigned short f2bf(float f){
  unsigned u = __float_as_uint(f);
  return (unsigned short)((u + 0x7FFFu + ((u >> 16) & 1u)) >> 16);
}
__device__ __forceinline__ float bf2f(unsigned short s){ return __uint_as_float(((unsigned)s) << 16); }

// ---------------- CSR build ----------------
__global__ void k_count(const int* __restrict__ ei, int* __restrict__ cnt){
  int e = blockIdx.x*256 + threadIdx.x;
  if (e < N_EDGES) atomicAdd(&cnt[ei[N_EDGES + e]], 1);
}

__global__ void k_scan1(const int* __restrict__ cnt, int* __restrict__ rowp, int* __restrict__ part){
  __shared__ int s[256];
  int t = threadIdx.x;
  int i = blockIdx.x*256 + t;
  int v = (i < N_NODES) ? cnt[i] : 0;
  s[t] = v;
  __syncthreads();
  #pragma unroll
  for (int off=1; off<256; off<<=1){
    int x = s[t];
    int y = (t >= off) ? s[t-off] : 0;
    __syncthreads();
    s[t] = x + y;
    __syncthreads();
  }
  if (i < N_NODES) rowp[i+1] = s[t];
  if (t == 255) part[blockIdx.x] = s[255];
}

__global__ void k_scan2(int* __restrict__ part){
  __shared__ int s[256];
  int t = threadIdx.x;
  int v = (t < NBLK) ? part[t] : 0;
  s[t] = v;
  __syncthreads();
  #pragma unroll
  for (int off=1; off<256; off<<=1){
    int x = s[t];
    int y = (t >= off) ? s[t-off] : 0;
    __syncthreads();
    s[t] = x + y;
    __syncthreads();
  }
  if (t < NBLK) part[t] = s[t] - v;   // exclusive offsets
}

__global__ void k_scan3(const int* __restrict__ cnt, int* __restrict__ rowp,
                        const int* __restrict__ part, float* __restrict__ dinv){
  int i = blockIdx.x*256 + threadIdx.x;
  if (i < N_NODES){
    rowp[i+1] += part[blockIdx.x];
    dinv[i] = rsqrtf(1.0f + (float)cnt[i]);
  }
  if (i == 0) rowp[0] = 0;
}

__global__ void k_fill(const int* __restrict__ ei, const int* __restrict__ rowp, int* __restrict__ fill,
                       const float* __restrict__ dinv, int* __restrict__ csrs, float* __restrict__ csrw){
  int e = blockIdx.x*256 + threadIdx.x;
  if (e >= N_EDGES) return;
  int sr = ei[e];
  int ds = ei[N_EDGES + e];
  int pos = rowp[ds] + atomicAdd(&fill[ds], 1);
  csrs[pos] = sr;
  csrw[pos] = dinv[sr] * dinv[ds];
}

// ---------------- BN fold: S = gamma*rsqrt(var+eps), T = (b - mu)*S + beta ----------------
__global__ void k_bnprep(const float* __restrict__ gcnb, const float* __restrict__ bng,
                         const float* __restrict__ bnb, const float* __restrict__ bnm,
                         const float* __restrict__ bnv, float* __restrict__ S, float* __restrict__ T){
  int idx = blockIdx.x*256 + threadIdx.x;
  if (idx >= NLAYERS*HDIM) return;
  float s = bng[idx] * rsqrtf(bnv[idx] + BN_EPSF);
  S[idx] = s;
  T[idx] = (gcnb[idx] - bnm[idx]) * s + bnb[idx];
}

// ---------------- weight prep: Wt[c][k] = bf16(W[k][c]) ----------------
__global__ void k_wt(const float* __restrict__ W, unsigned short* __restrict__ Wt, int Kd, int Cd){
  int idx = blockIdx.x*256 + threadIdx.x;
  if (idx >= Kd*Cd) return;
  int c = idx / Kd, k = idx - c*Kd;
  Wt[idx] = f2bf(W[(size_t)k*Cd + c]);
}

// ---------------- f32 -> bf16 convert (n multiple of 4) ----------------
__global__ void k_cvt(const float* __restrict__ in, unsigned short* __restrict__ out, int n4){
  int i = blockIdx.x*256 + threadIdx.x;
  if (i >= n4) return;
  float4 v = ld4(in + (size_t)i*4);
  ushort4 o;
  o.x = f2bf(v.x); o.y = f2bf(v.y); o.z = f2bf(v.z); o.w = f2bf(v.w);
  *reinterpret_cast<ushort4*>(out + (size_t)i*4) = o;
}

// ---------------- bf16 MFMA GEMM: 128x128 tile, BK=64, 4 waves (2x2), 64x64 per wave ----------------
template<int K, bool EMB>
__global__ __launch_bounds__(256) void k_mgemm(const unsigned short* __restrict__ A,
                                               const unsigned short* __restrict__ Wt,
                                               const float* __restrict__ bias,
                                               unsigned short* __restrict__ mout,
                                               float* __restrict__ hf,
                                               unsigned short* __restrict__ hb,
                                               int nrows){
  __shared__ unsigned short As[128][72];   // [row][k]
  __shared__ unsigned short Bs[128][72];   // [col][k]
  const int t = threadIdx.x;
  const int lane = t & 63;
  const int wid = t >> 6;
  const int wm = wid >> 1, wn = wid & 1;
  const int row0 = blockIdx.x * 128;
  const int col0 = blockIdx.y * 128;

  f32x4 acc[4][4];
  #pragma unroll
  for (int i=0;i<4;i++)
    #pragma unroll
    for (int j=0;j<4;j++) acc[i][j] = (f32x4){0.f,0.f,0.f,0.f};

  for (int k0 = 0; k0 < K; k0 += 64){
    #pragma unroll
    for (int i=0;i<4;i++){
      int chunk = t + i*256;
      int row = chunk >> 3;
      int kc = (chunk & 7) * 8;
      int gr = row0 + row;
      int4 v = make_int4(0,0,0,0);
      if (gr < nrows) v = *reinterpret_cast<const int4*>(A + (size_t)gr*K + k0 + kc);
      *reinterpret_cast<int4*>(&As[row][kc]) = v;
    }
    #pragma unroll
    for (int i=0;i<4;i++){
      int chunk = t + i*256;
      int col = chunk >> 3;
      int kc = (chunk & 7) * 8;
      int4 v = *reinterpret_cast<const int4*>(Wt + (size_t)(col0+col)*K + k0 + kc);
      *reinterpret_cast<int4*>(&Bs[col][kc]) = v;
    }
    __syncthreads();
    #pragma unroll
    for (int kk=0; kk<64; kk+=32){
      const int kofs = kk + (lane >> 4) * 8;
      short8 af[4], bfv[4];
      #pragma unroll
      for (int mi=0;mi<4;mi++)
        af[mi] = *reinterpret_cast<const short8*>(&As[wm*64 + mi*16 + (lane & 15)][kofs]);
      #pragma unroll
      for (int ni=0;ni<4;ni++)
        bfv[ni] = *reinterpret_cast<const short8*>(&Bs[wn*64 + ni*16 + (lane & 15)][kofs]);
      #pragma unroll
      for (int mi=0;mi<4;mi++)
        #pragma unroll
        for (int ni=0;ni<4;ni++)
          acc[mi][ni] = __builtin_amdgcn_mfma_f32_16x16x32_bf16(af[mi], bfv[ni], acc[mi][ni], 0, 0, 0);
    }
    __syncthreads();
  }

  const int crow = row0 + wm*64;
  const int ccol = col0 + wn*64 + (lane & 15);
  #pragma unroll
  for (int mi=0;mi<4;mi++){
    #pragma unroll
    for (int j=0;j<4;j++){
      int gr = crow + mi*16 + (lane >> 4)*4 + j;
      if (gr < nrows){
        #pragma unroll
        for (int ni=0;ni<4;ni++){
          float v = acc[mi][ni][j];
          int gc = ccol + ni*16;
          if (EMB){
            v = fmaxf(v + bias[gc], 0.f);
            hf[(size_t)gr*HDIM + gc] = v;
            hb[(size_t)gr*HDIM + gc] = f2bf(v);
          } else {
            mout[(size_t)gr*HDIM + gc] = f2bf(v);
          }
        }
      }
    }
  }
}

// ---------------- fused aggregation: half-wave edge split, ushort8 gathers ----------------
// one wave per node; lanes 0-31 even edges, 32-63 odd edges; lane owns 8 channels.
template<bool WHB>
__global__ __launch_bounds__(256) void k_agg(const unsigned short* __restrict__ m, const int* __restrict__ rowp,
                                             const int* __restrict__ csrs, const float* __restrict__ csrw,
                                             const float* __restrict__ dinv,
                                             const float* __restrict__ S, const float* __restrict__ T,
                                             float* __restrict__ h, unsigned short* __restrict__ hb){
  int node = blockIdx.x*4 + (threadIdx.x >> 6);
  int lane = threadIdx.x & 63;
  int half = lane >> 5;
  int c = (lane & 31) * 8;

  float acc[8];
  const size_t base = (size_t)node*HDIM + c;
  if (half == 0){
    float dn = dinv[node];
    float sn = dn * dn;
    u16x8 ms = *reinterpret_cast<const u16x8*>(m + base);
    #pragma unroll
    for (int j=0;j<8;j++) acc[j] = bf2f(ms[j]) * sn;
  } else {
    #pragma unroll
    for (int j=0;j<8;j++) acc[j] = 0.f;
  }

  int s = rowp[node], e = rowp[node+1];
  int i = s + half;
  for (; i + 2 < e; i += 4){
    int s0 = csrs[i],   s1 = csrs[i+2];
    float w0 = csrw[i], w1 = csrw[i+2];
    u16x8 m0 = *reinterpret_cast<const u16x8*>(m + (size_t)s0*HDIM + c);
    u16x8 m1 = *reinterpret_cast<const u16x8*>(m + (size_t)s1*HDIM + c);
    #pragma unroll
    for (int j=0;j<8;j++) acc[j] += w0*bf2f(m0[j]) + w1*bf2f(m1[j]);
  }
  if (i < e){
    int s0 = csrs[i]; float w0 = csrw[i];
    u16x8 m0 = *reinterpret_cast<const u16x8*>(m + (size_t)s0*HDIM + c);
    #pragma unroll
    for (int j=0;j<8;j++) acc[j] += w0*bf2f(m0[j]);
  }

  // cross-half combine
  #pragma unroll
  for (int j=0;j<8;j++) acc[j] += __shfl_xor(acc[j], 32);

  if (half == 0){
    float4 S0 = ld4(S + c), S1 = ld4(S + c + 4);
    float4 T0 = ld4(T + c), T1 = ld4(T + c + 4);
    float4 h0 = ld4(h + base), h1 = ld4(h + base + 4);
    float o[8];
    o[0] = fmaxf(acc[0]*S0.x + T0.x, 0.f) + h0.x;
    o[1] = fmaxf(acc[1]*S0.y + T0.y, 0.f) + h0.y;
    o[2] = fmaxf(acc[2]*S0.z + T0.z, 0.f) + h0.z;
    o[3] = fmaxf(acc[3]*S0.w + T0.w, 0.f) + h0.w;
    o[4] = fmaxf(acc[4]*S1.x + T1.x, 0.f) + h1.x;
    o[5] = fmaxf(acc[5]*S1.y + T1.y, 0.f) + h1.y;
    o[6] = fmaxf(acc[6]*S1.z + T1.z, 0.f) + h1.z;
    o[7] = fmaxf(acc[7]*S1.w + T1.w, 0.f) + h1.w;
    st4(h + base,     make_float4(o[0],o[1],o[2],o[3]));
    st4(h + base + 4, make_float4(o[4],o[5],o[6],o[7]));
    if (WHB){
      u16x8 ob;
      #pragma unroll
      for (int j=0;j<8;j++) ob[j] = f2bf(o[j]);
      *reinterpret_cast<u16x8*>(hb + base) = ob;
    }
  }
}

// ---------------- global mean pool (batch_idx sorted) ----------------
__device__ __forceinline__ int lbound(const int* __restrict__ a, int n, int key){
  int lo = 0, hi = n;
  while (lo < hi){ int mid = (lo + hi) >> 1; if (a[mid] < key) lo = mid + 1; else hi = mid; }
  return lo;
}

__global__ __launch_bounds__(256) void k_pool(const float* __restrict__ h, const int* __restrict__ batch,
                                              float* __restrict__ g){
  int gi = blockIdx.x;
  int lo = lbound(batch, N_NODES, gi);
  int hi = lbound(batch, N_NODES, gi + 1);
  float sum = 0.f;
  for (int n = lo; n < hi; ++n) sum += h[(size_t)n*HDIM + threadIdx.x];
  float inv = 1.0f / fmaxf((float)(hi - lo), 1.0f);
  g[(size_t)gi*HDIM + threadIdx.x] = sum * inv;
}

// ---------------- fused 3-layer property heads, GB graphs per block ----------------
__global__ __launch_bounds__(128) void k_heads(const float* __restrict__ g,
                                               const float* __restrict__ W1, const float* __restrict__ b1,
                                               const float* __restrict__ W2, const float* __restrict__ b2,
                                               const float* __restrict__ W3, const float* __restrict__ b3,
                                               float* __restrict__ out){
  int g0 = blockIdx.x * GB, p = blockIdx.y;
  __shared__ float gs[GB][HDIM];
  __shared__ float z1[GB][128];
  int t = threadIdx.x;
  #pragma unroll
  for (int gi=0; gi<GB; gi++){
    gs[gi][t]       = g[(size_t)(g0+gi)*HDIM + t];
    gs[gi][t + 128] = g[(size_t)(g0+gi)*HDIM + t + 128];
  }
  __syncthreads();

  const float* w1 = W1 + (size_t)p*HDIM*128;
  float a[GB];
  #pragma unroll
  for (int gi=0; gi<GB; gi++) a[gi] = 0.f;
  for (int i=0;i<HDIM;i++){
    float wv = w1[(size_t)i*128 + t];
    #pragma unroll
    for (int gi=0; gi<GB; gi++) a[gi] += gs[gi][i] * wv;
  }
  float b1v = b1[p*128 + t];
  #pragma unroll
  for (int gi=0; gi<GB; gi++) z1[gi][t] = fmaxf(a[gi] + b1v, 0.f);
  __syncthreads();

  if (t < 64){
    const float* w2 = W2 + (size_t)p*128*64;
    float a2[GB];
    #pragma unroll
    for (int gi=0; gi<GB; gi++) a2[gi] = 0.f;
    for (int i=0;i<128;i++){
      float wv = w2[(size_t)i*64 + t];
      #pragma unroll
      for (int gi=0; gi<GB; gi++) a2[gi] += z1[gi][i] * wv;
    }
    float w3v = W3[p*64 + t];
    float b2v = b2[p*64 + t];
    float b3v = b3[p];
    #pragma unroll
    for (int gi=0; gi<GB; gi++){
      float z2 = fmaxf(a2[gi] + b2v, 0.f);
      float v = z2 * w3v;
      #pragma unroll
      for (int off=32; off>0; off>>=1) v += __shfl_down(v, off, 64);
      if (t == 0) out[(size_t)(g0+gi)*NPROPS + p] = v + b3v;
    }
  }
}

// ---------------- launch ----------------
extern "C" void kernel_launch(void* const* d_in, const int* in_sizes, int n_in,
                              void* d_out, int out_size, void* d_ws, size_t ws_size,
                              hipStream_t stream){
  const float* x     = (const float*)d_in[0];
  const int*   ei    = (const int*)  d_in[1];
  const int*   batch = (const int*)  d_in[2];
  const float* embW  = (const float*)d_in[3];
  const float* embb  = (const float*)d_in[4];
  const float* gcnW  = (const float*)d_in[5];
  const float* gcnb  = (const float*)d_in[6];
  const float* bng   = (const float*)d_in[7];
  const float* bnb   = (const float*)d_in[8];
  const float* bnm   = (const float*)d_in[9];
  const float* bnv   = (const float*)d_in[10];
  const float* h1W   = (const float*)d_in[11];
  const float* h1b   = (const float*)d_in[12];
  const float* h2W   = (const float*)d_in[13];
  const float* h2b   = (const float*)d_in[14];
  const float* h3W   = (const float*)d_in[15];
  const float* h3b   = (const float*)d_in[16];
  float* out = (float*)d_out;

  char* w = (char*)d_ws;
  auto alloc = [&](size_t bytes)->char*{ char* p = w; w += (bytes + 255) & ~(size_t)255; return p; };
  float*          h    = (float*)         alloc((size_t)N_NODES*HDIM*4);
  unsigned short* hb   = (unsigned short*)alloc((size_t)N_NODES*HDIM*2);
  unsigned short* m    = (unsigned short*)alloc((size_t)N_NODES*HDIM*2);
  int*   cnt  = (int*)  alloc((size_t)N_NODES*4);
  int*   fill = (int*)  alloc((size_t)N_NODES*4);
  int*   rowp = (int*)  alloc((size_t)(N_NODES+1)*4);
  float* dinv = (float*)alloc((size_t)N_NODES*4);
  int*   csrs = (int*)  alloc((size_t)N_EDGES*4);
  float* csrw = (float*)alloc((size_t)N_EDGES*4);
  int*   part = (int*)  alloc(1024);
  float* gp   = (float*)alloc((size_t)N_GRAPHS*HDIM*4);
  unsigned short* embWt = (unsigned short*)alloc((size_t)NODE_DIMC*HDIM*2);
  unsigned short* gcnWt = (unsigned short*)alloc((size_t)NLAYERS*HDIM*HDIM*2);
  float* bnS  = (float*)alloc((size_t)NLAYERS*HDIM*4);
  float* bnT  = (float*)alloc((size_t)NLAYERS*HDIM*4);

  hipMemsetAsync(cnt, 0, (size_t)N_NODES*4, stream);
  hipMemsetAsync(fill, 0, (size_t)N_NODES*4, stream);

  const int EB = (N_EDGES + 255)/256;
  k_count<<<EB,256,0,stream>>>(ei, cnt);
  k_scan1<<<NBLK,256,0,stream>>>(cnt, rowp, part);
  k_scan2<<<1,256,0,stream>>>(part);
  k_scan3<<<NBLK,256,0,stream>>>(cnt, rowp, part, dinv);
  k_fill<<<EB,256,0,stream>>>(ei, rowp, fill, dinv, csrs, csrw);

  k_bnprep<<<(NLAYERS*HDIM + 255)/256,256,0,stream>>>(gcnb, bng, bnb, bnm, bnv, bnS, bnT);
  k_wt<<<(NODE_DIMC*HDIM + 255)/256,256,0,stream>>>(embW, embWt, NODE_DIMC, HDIM);
  for (int l = 0; l < NLAYERS; ++l)
    k_wt<<<(HDIM*HDIM + 255)/256,256,0,stream>>>(gcnW + (size_t)l*HDIM*HDIM, gcnWt + (size_t)l*HDIM*HDIM, HDIM, HDIM);

  unsigned short* xb = m;
  k_cvt<<<(N_NODES*NODE_DIMC/4 + 255)/256,256,0,stream>>>(x, xb, N_NODES*NODE_DIMC/4);

  const int RB = (N_NODES + 127)/128;
  k_mgemm<NODE_DIMC, true><<<dim3(RB,2),256,0,stream>>>(xb, embWt, embb, nullptr, h, hb, N_NODES);

  for (int l = 0; l < NLAYERS; ++l){
    k_mgemm<HDIM, false><<<dim3(RB,2),256,0,stream>>>(hb, gcnWt + (size_t)l*HDIM*HDIM, nullptr, m, nullptr, nullptr, N_NODES);
    if (l < NLAYERS-1)
      k_agg<true ><<<(N_NODES+3)/4,256,0,stream>>>(m, rowp, csrs, csrw, dinv,
                                                   bnS + l*HDIM, bnT + l*HDIM, h, hb);
    else
      k_agg<false><<<(N_NODES+3)/4,256,0,stream>>>(m, rowp, csrs, csrw, dinv,
                                                   bnS + l*HDIM, bnT + l*HDIM, h, hb);
  }

  k_pool<<<N_GRAPHS,256,0,stream>>>(h, batch, gp);
  k_heads<<<dim3((N_GRAPHS+GB-1)/GB,NPROPS),128,0,stream>>>(gp, h1W, h1b, h2W, h2b, h3W, h3b, out);
}

// Round 4
// 525.190 us; speedup vs baseline: 1.9972x; 1.0649x over previous
//
#include <hip/hip_runtime.h>

#define N_NODES 50000
#define N_EDGES 800000
#define N_GRAPHS 1000
#define NODE_DIMC 128
#define HDIM 256
#define NLAYERS 4
#define NPROPS 3
#define BN_EPSF 1e-5f
#define NBLK 196   // ceil(N_NODES/256)
#define GB 8       // graphs per head-block

typedef __attribute__((ext_vector_type(4))) float f32x4;
typedef __attribute__((ext_vector_type(8))) short short8;
typedef __attribute__((ext_vector_type(8))) unsigned short u16x8;

__device__ __forceinline__ float4 ld4(const float* p){ return *reinterpret_cast<const float4*>(p); }
__device__ __forceinline__ void st4(float* p, float4 v){ *reinterpret_cast<float4*>(p) = v; }
__device__ __forceinline__ unsigned short f2bf(float f){
  unsigned u = __float_as_uint(f);
  return (unsigned short)((u + 0x7FFFu + ((u >> 16) & 1u)) >> 16);
}
__device__ __forceinline__ float bf2f(unsigned short s){ return __uint_as_float(((unsigned)s) << 16); }

__device__ __forceinline__ void gl2lds16(const void* g, void* l){
  __builtin_amdgcn_global_load_lds((const __attribute__((address_space(1))) unsigned int*)g,
                                   (__attribute__((address_space(3))) unsigned int*)l, 16, 0, 0);
}

// ---------------- CSR build ----------------
__global__ void k_count(const int* __restrict__ ei, int* __restrict__ cnt){
  int e = blockIdx.x*256 + threadIdx.x;
  if (e < N_EDGES) atomicAdd(&cnt[ei[N_EDGES + e]], 1);
}

__global__ void k_scan1(const int* __restrict__ cnt, int* __restrict__ rowp, int* __restrict__ part){
  __shared__ int s[256];
  int t = threadIdx.x;
  int i = blockIdx.x*256 + t;
  int v = (i < N_NODES) ? cnt[i] : 0;
  s[t] = v;
  __syncthreads();
  #pragma unroll
  for (int off=1; off<256; off<<=1){
    int x = s[t];
    int y = (t >= off) ? s[t-off] : 0;
    __syncthreads();
    s[t] = x + y;
    __syncthreads();
  }
  if (i < N_NODES) rowp[i+1] = s[t];
  if (t == 255) part[blockIdx.x] = s[255];
}

__global__ void k_scan2(int* __restrict__ part){
  __shared__ int s[256];
  int t = threadIdx.x;
  int v = (t < NBLK) ? part[t] : 0;
  s[t] = v;
  __syncthreads();
  #pragma unroll
  for (int off=1; off<256; off<<=1){
    int x = s[t];
    int y = (t >= off) ? s[t-off] : 0;
    __syncthreads();
    s[t] = x + y;
    __syncthreads();
  }
  if (t < NBLK) part[t] = s[t] - v;   // exclusive offsets
}

__global__ void k_scan3(const int* __restrict__ cnt, int* __restrict__ rowp,
                        const int* __restrict__ part, float* __restrict__ dinv){
  int i = blockIdx.x*256 + threadIdx.x;
  if (i < N_NODES){
    rowp[i+1] += part[blockIdx.x];
    dinv[i] = rsqrtf(1.0f + (float)cnt[i]);
  }
  if (i == 0) rowp[0] = 0;
}

__global__ void k_fill(const int* __restrict__ ei, const int* __restrict__ rowp, int* __restrict__ fill,
                       const float* __restrict__ dinv, int* __restrict__ csrs, float* __restrict__ csrw){
  int e = blockIdx.x*256 + threadIdx.x;
  if (e >= N_EDGES) return;
  int sr = ei[e];
  int ds = ei[N_EDGES + e];
  int pos = rowp[ds] + atomicAdd(&fill[ds], 1);
  csrs[pos] = sr;
  csrw[pos] = dinv[sr] * dinv[ds];
}

// ---------------- fused prep: x->bf16, embWt, gcnWt, BN fold ----------------
#define XCVT_N (N_NODES*NODE_DIMC/4)               // 1,600,000 float4 items
#define EMBWT_N (NODE_DIMC*HDIM)                   // 32768
#define GCNWT_N (NLAYERS*HDIM*HDIM)                // 262144
#define BN_N (NLAYERS*HDIM)                        // 1024
#define PREP_TOTAL (XCVT_N + EMBWT_N + GCNWT_N + BN_N)

__global__ void k_prep(const float* __restrict__ x, unsigned short* __restrict__ xb,
                       const float* __restrict__ embW, unsigned short* __restrict__ embWt,
                       const float* __restrict__ gcnW, unsigned short* __restrict__ gcnWt,
                       const float* __restrict__ gcnb, const float* __restrict__ bng,
                       const float* __restrict__ bnb, const float* __restrict__ bnm,
                       const float* __restrict__ bnv, float* __restrict__ S, float* __restrict__ T){
  int idx = blockIdx.x*256 + threadIdx.x;
  if (idx < XCVT_N){
    float4 v = ld4(x + (size_t)idx*4);
    ushort4 o;
    o.x = f2bf(v.x); o.y = f2bf(v.y); o.z = f2bf(v.z); o.w = f2bf(v.w);
    *reinterpret_cast<ushort4*>(xb + (size_t)idx*4) = o;
    return;
  }
  idx -= XCVT_N;
  if (idx < EMBWT_N){
    int c = idx >> 7, k = idx & 127;
    embWt[idx] = f2bf(embW[(size_t)k*HDIM + c]);
    return;
  }
  idx -= EMBWT_N;
  if (idx < GCNWT_N){
    int l = idx >> 16, rem = idx & 65535;
    int c = rem >> 8, k = rem & 255;
    gcnWt[idx] = f2bf(gcnW[(size_t)l*HDIM*HDIM + (size_t)k*HDIM + c]);
    return;
  }
  idx -= GCNWT_N;
  if (idx < BN_N){
    float s = bng[idx] * rsqrtf(bnv[idx] + BN_EPSF);
    S[idx] = s;
    T[idx] = (gcnb[idx] - bnm[idx]) * s + bnb[idx];
  }
}

// ---------------- bf16 MFMA GEMM: 128x128 tile, BK=64, 4 waves (2x2) ----------------
// LDS staged via global_load_lds (linear dest) with XOR-swizzled source; reads un-swizzle.
template<int K, bool EMB>
__global__ __launch_bounds__(256) void k_mgemm(const unsigned short* __restrict__ A,
                                               const unsigned short* __restrict__ Wt,
                                               const float* __restrict__ bias,
                                               unsigned short* __restrict__ mout,
                                               float* __restrict__ hf,
                                               unsigned short* __restrict__ hb,
                                               int nrows){
  __shared__ unsigned short As[128*64];   // linear 16KB, swizzled content
  __shared__ unsigned short Bs[128*64];
  const int t = threadIdx.x;
  const int lane = t & 63;
  const int wid = t >> 6;
  const int wm = wid >> 1, wn = wid & 1;
  const int row0 = blockIdx.x * 128;
  const int col0 = blockIdx.y * 128;

  // per-lane swizzled source column (shorts) and row-within-chunk for staging
  const int scol = 8 * ((lane & 7) ^ (lane >> 3));
  const int srow = lane >> 3;
  const int rx = (lane & 7) << 3;   // read-side XOR (shorts)

  f32x4 acc[4][4];
  #pragma unroll
  for (int i=0;i<4;i++)
    #pragma unroll
    for (int j=0;j<4;j++) acc[i][j] = (f32x4){0.f,0.f,0.f,0.f};

  for (int k0 = 0; k0 < K; k0 += 64){
    #pragma unroll
    for (int i=0;i<4;i++){
      int chunkid = wid*4 + i;                 // 0..15, 8 rows each
      int r = chunkid*8 + srow;
      gl2lds16(A + (size_t)(row0 + r)*K + k0 + scol, As + chunkid*512);
    }
    #pragma unroll
    for (int i=0;i<4;i++){
      int chunkid = wid*4 + i;
      int r = chunkid*8 + srow;
      gl2lds16(Wt + (size_t)(col0 + r)*K + k0 + scol, Bs + chunkid*512);
    }
    __syncthreads();
    #pragma unroll
    for (int kk=0; kk<64; kk+=32){
      const int kofs = kk + (lane >> 4) * 8;
      short8 af[4], bfv[4];
      #pragma unroll
      for (int mi=0;mi<4;mi++){
        int r = wm*64 + mi*16 + (lane & 15);
        af[mi] = *reinterpret_cast<const short8*>(&As[(r*64 + kofs) ^ rx]);
      }
      #pragma unroll
      for (int ni=0;ni<4;ni++){
        int r = wn*64 + ni*16 + (lane & 15);
        bfv[ni] = *reinterpret_cast<const short8*>(&Bs[(r*64 + kofs) ^ rx]);
      }
      #pragma unroll
      for (int mi=0;mi<4;mi++)
        #pragma unroll
        for (int ni=0;ni<4;ni++)
          acc[mi][ni] = __builtin_amdgcn_mfma_f32_16x16x32_bf16(af[mi], bfv[ni], acc[mi][ni], 0, 0, 0);
    }
    __syncthreads();
  }

  const int crow = row0 + wm*64;
  const int ccol = col0 + wn*64 + (lane & 15);
  #pragma unroll
  for (int mi=0;mi<4;mi++){
    #pragma unroll
    for (int j=0;j<4;j++){
      int gr = crow + mi*16 + (lane >> 4)*4 + j;
      if (gr < nrows){
        #pragma unroll
        for (int ni=0;ni<4;ni++){
          float v = acc[mi][ni][j];
          int gc = ccol + ni*16;
          if (EMB){
            v = fmaxf(v + bias[gc], 0.f);
            hf[(size_t)gr*HDIM + gc] = v;
            hb[(size_t)gr*HDIM + gc] = f2bf(v);
          } else {
            mout[(size_t)gr*HDIM + gc] = f2bf(v);
          }
        }
      }
    }
  }
}

// ---------------- fused aggregation: half-wave edge split, 4-way unroll, ushort8 gathers ----------------
template<bool WHB>
__global__ __launch_bounds__(256) void k_agg(const unsigned short* __restrict__ m, const int* __restrict__ rowp,
                                             const int* __restrict__ csrs, const float* __restrict__ csrw,
                                             const float* __restrict__ dinv,
                                             const float* __restrict__ S, const float* __restrict__ T,
                                             float* __restrict__ h, unsigned short* __restrict__ hb){
  int node = blockIdx.x*4 + (threadIdx.x >> 6);
  int lane = threadIdx.x & 63;
  int half = lane >> 5;
  int c = (lane & 31) * 8;

  float acc[8];
  const size_t base = (size_t)node*HDIM + c;
  if (half == 0){
    float dn = dinv[node];
    float sn = dn * dn;
    u16x8 ms = *reinterpret_cast<const u16x8*>(m + base);
    #pragma unroll
    for (int j=0;j<8;j++) acc[j] = bf2f(ms[j]) * sn;
  } else {
    #pragma unroll
    for (int j=0;j<8;j++) acc[j] = 0.f;
  }

  int s = rowp[node], e = rowp[node+1];
  int i = s + half;
  // 4 gathers in flight per half-lane
  for (; i + 6 < e; i += 8){
    int s0 = csrs[i],   s1 = csrs[i+2], s2 = csrs[i+4], s3 = csrs[i+6];
    float w0 = csrw[i], w1 = csrw[i+2], w2 = csrw[i+4], w3 = csrw[i+6];
    u16x8 m0 = *reinterpret_cast<const u16x8*>(m + (size_t)s0*HDIM + c);
    u16x8 m1 = *reinterpret_cast<const u16x8*>(m + (size_t)s1*HDIM + c);
    u16x8 m2 = *reinterpret_cast<const u16x8*>(m + (size_t)s2*HDIM + c);
    u16x8 m3 = *reinterpret_cast<const u16x8*>(m + (size_t)s3*HDIM + c);
    #pragma unroll
    for (int j=0;j<8;j++){
      acc[j] += w0*bf2f(m0[j]) + w1*bf2f(m1[j]);
      acc[j] += w2*bf2f(m2[j]) + w3*bf2f(m3[j]);
    }
  }
  if (i + 2 < e){
    int s0 = csrs[i], s1 = csrs[i+2];
    float w0 = csrw[i], w1 = csrw[i+2];
    u16x8 m0 = *reinterpret_cast<const u16x8*>(m + (size_t)s0*HDIM + c);
    u16x8 m1 = *reinterpret_cast<const u16x8*>(m + (size_t)s1*HDIM + c);
    #pragma unroll
    for (int j=0;j<8;j++) acc[j] += w0*bf2f(m0[j]) + w1*bf2f(m1[j]);
    i += 4;
  }
  if (i < e){
    int s0 = csrs[i]; float w0 = csrw[i];
    u16x8 m0 = *reinterpret_cast<const u16x8*>(m + (size_t)s0*HDIM + c);
    #pragma unroll
    for (int j=0;j<8;j++) acc[j] += w0*bf2f(m0[j]);
  }

  // cross-half combine
  #pragma unroll
  for (int j=0;j<8;j++) acc[j] += __shfl_xor(acc[j], 32);

  if (half == 0){
    float4 S0 = ld4(S + c), S1 = ld4(S + c + 4);
    float4 T0 = ld4(T + c), T1 = ld4(T + c + 4);
    float4 h0 = ld4(h + base), h1 = ld4(h + base + 4);
    float o[8];
    o[0] = fmaxf(acc[0]*S0.x + T0.x, 0.f) + h0.x;
    o[1] = fmaxf(acc[1]*S0.y + T0.y, 0.f) + h0.y;
    o[2] = fmaxf(acc[2]*S0.z + T0.z, 0.f) + h0.z;
    o[3] = fmaxf(acc[3]*S0.w + T0.w, 0.f) + h0.w;
    o[4] = fmaxf(acc[4]*S1.x + T1.x, 0.f) + h1.x;
    o[5] = fmaxf(acc[5]*S1.y + T1.y, 0.f) + h1.y;
    o[6] = fmaxf(acc[6]*S1.z + T1.z, 0.f) + h1.z;
    o[7] = fmaxf(acc[7]*S1.w + T1.w, 0.f) + h1.w;
    st4(h + base,     make_float4(o[0],o[1],o[2],o[3]));
    st4(h + base + 4, make_float4(o[4],o[5],o[6],o[7]));
    if (WHB){
      u16x8 ob;
      #pragma unroll
      for (int j=0;j<8;j++) ob[j] = f2bf(o[j]);
      *reinterpret_cast<u16x8*>(hb + base) = ob;
    }
  }
}

// ---------------- global mean pool (batch_idx sorted) ----------------
__device__ __forceinline__ int lbound(const int* __restrict__ a, int n, int key){
  int lo = 0, hi = n;
  while (lo < hi){ int mid = (lo + hi) >> 1; if (a[mid] < key) lo = mid + 1; else hi = mid; }
  return lo;
}

__global__ __launch_bounds__(256) void k_pool(const float* __restrict__ h, const int* __restrict__ batch,
                                              float* __restrict__ g){
  int gi = blockIdx.x;
  int lo = lbound(batch, N_NODES, gi);
  int hi = lbound(batch, N_NODES, gi + 1);
  float sum = 0.f;
  for (int n = lo; n < hi; ++n) sum += h[(size_t)n*HDIM + threadIdx.x];
  float inv = 1.0f / fmaxf((float)(hi - lo), 1.0f);
  g[(size_t)gi*HDIM + threadIdx.x] = sum * inv;
}

// ---------------- fused 3-layer property heads, GB graphs per block ----------------
__global__ __launch_bounds__(128) void k_heads(const float* __restrict__ g,
                                               const float* __restrict__ W1, const float* __restrict__ b1,
                                               const float* __restrict__ W2, const float* __restrict__ b2,
                                               const float* __restrict__ W3, const float* __restrict__ b3,
                                               float* __restrict__ out){
  int g0 = blockIdx.x * GB, p = blockIdx.y;
  __shared__ float gs[GB][HDIM];
  __shared__ float z1[GB][128];
  int t = threadIdx.x;
  #pragma unroll
  for (int gi=0; gi<GB; gi++){
    gs[gi][t]       = g[(size_t)(g0+gi)*HDIM + t];
    gs[gi][t + 128] = g[(size_t)(g0+gi)*HDIM + t + 128];
  }
  __syncthreads();

  const float* w1 = W1 + (size_t)p*HDIM*128;
  float a[GB];
  #pragma unroll
  for (int gi=0; gi<GB; gi++) a[gi] = 0.f;
  for (int i=0;i<HDIM;i++){
    float wv = w1[(size_t)i*128 + t];
    #pragma unroll
    for (int gi=0; gi<GB; gi++) a[gi] += gs[gi][i] * wv;
  }
  float b1v = b1[p*128 + t];
  #pragma unroll
  for (int gi=0; gi<GB; gi++) z1[gi][t] = fmaxf(a[gi] + b1v, 0.f);
  __syncthreads();

  if (t < 64){
    const float* w2 = W2 + (size_t)p*128*64;
    float a2[GB];
    #pragma unroll
    for (int gi=0; gi<GB; gi++) a2[gi] = 0.f;
    for (int i=0;i<128;i++){
      float wv = w2[(size_t)i*64 + t];
      #pragma unroll
      for (int gi=0; gi<GB; gi++) a2[gi] += z1[gi][i] * wv;
    }
    float w3v = W3[p*64 + t];
    float b2v = b2[p*64 + t];
    float b3v = b3[p];
    #pragma unroll
    for (int gi=0; gi<GB; gi++){
      float z2 = fmaxf(a2[gi] + b2v, 0.f);
      float v = z2 * w3v;
      #pragma unroll
      for (int off=32; off>0; off>>=1) v += __shfl_down(v, off, 64);
      if (t == 0) out[(size_t)(g0+gi)*NPROPS + p] = v + b3v;
    }
  }
}

// ---------------- launch ----------------
extern "C" void kernel_launch(void* const* d_in, const int* in_sizes, int n_in,
                              void* d_out, int out_size, void* d_ws, size_t ws_size,
                              hipStream_t stream){
  const float* x     = (const float*)d_in[0];
  const int*   ei    = (const int*)  d_in[1];
  const int*   batch = (const int*)  d_in[2];
  const float* embW  = (const float*)d_in[3];
  const float* embb  = (const float*)d_in[4];
  const float* gcnW  = (const float*)d_in[5];
  const float* gcnb  = (const float*)d_in[6];
  const float* bng   = (const float*)d_in[7];
  const float* bnb   = (const float*)d_in[8];
  const float* bnm   = (const float*)d_in[9];
  const float* bnv   = (const float*)d_in[10];
  const float* h1W   = (const float*)d_in[11];
  const float* h1b   = (const float*)d_in[12];
  const float* h2W   = (const float*)d_in[13];
  const float* h2b   = (const float*)d_in[14];
  const float* h3W   = (const float*)d_in[15];
  const float* h3b   = (const float*)d_in[16];
  float* out = (float*)d_out;

  char* w = (char*)d_ws;
  auto alloc = [&](size_t bytes)->char*{ char* p = w; w += (bytes + 255) & ~(size_t)255; return p; };
  float*          h    = (float*)         alloc((size_t)N_NODES*HDIM*4);
  unsigned short* hb   = (unsigned short*)alloc((size_t)N_NODES*HDIM*2);
  unsigned short* m    = (unsigned short*)alloc((size_t)N_NODES*HDIM*2);
  int*   cnt  = (int*)  alloc((size_t)N_NODES*4);
  int*   fill = (int*)  alloc((size_t)N_NODES*4);
  int*   rowp = (int*)  alloc((size_t)(N_NODES+1)*4);
  float* dinv = (float*)alloc((size_t)N_NODES*4);
  int*   csrs = (int*)  alloc((size_t)N_EDGES*4);
  float* csrw = (float*)alloc((size_t)N_EDGES*4);
  int*   part = (int*)  alloc(1024);
  float* gp   = (float*)alloc((size_t)N_GRAPHS*HDIM*4);
  unsigned short* embWt = (unsigned short*)alloc((size_t)NODE_DIMC*HDIM*2);
  unsigned short* gcnWt = (unsigned short*)alloc((size_t)NLAYERS*HDIM*HDIM*2);
  float* bnS  = (float*)alloc((size_t)NLAYERS*HDIM*4);
  float* bnT  = (float*)alloc((size_t)NLAYERS*HDIM*4);

  hipMemsetAsync(cnt, 0, (size_t)N_NODES*4, stream);
  hipMemsetAsync(fill, 0, (size_t)N_NODES*4, stream);

  const int EB = (N_EDGES + 255)/256;
  k_count<<<EB,256,0,stream>>>(ei, cnt);
  k_scan1<<<NBLK,256,0,stream>>>(cnt, rowp, part);
  k_scan2<<<1,256,0,stream>>>(part);
  k_scan3<<<NBLK,256,0,stream>>>(cnt, rowp, part, dinv);
  k_fill<<<EB,256,0,stream>>>(ei, rowp, fill, dinv, csrs, csrw);

  unsigned short* xb = m;
  k_prep<<<(PREP_TOTAL + 255)/256,256,0,stream>>>(x, xb, embW, embWt, gcnW, gcnWt,
                                                  gcnb, bng, bnb, bnm, bnv, bnS, bnT);

  const int RB = (N_NODES + 127)/128;
  k_mgemm<NODE_DIMC, true><<<dim3(RB,2),256,0,stream>>>(xb, embWt, embb, nullptr, h, hb, N_NODES);

  for (int l = 0; l < NLAYERS; ++l){
    k_mgemm<HDIM, false><<<dim3(RB,2),256,0,stream>>>(hb, gcnWt + (size_t)l*HDIM*HDIM, nullptr, m, nullptr, nullptr, N_NODES);
    if (l < NLAYERS-1)
      k_agg<true ><<<(N_NODES+3)/4,256,0,stream>>>(m, rowp, csrs, csrw, dinv,
                                                   bnS + l*HDIM, bnT + l*HDIM, h, hb);
    else
      k_agg<false><<<(N_NODES+3)/4,256,0,stream>>>(m, rowp, csrs, csrw, dinv,
                                                   bnS + l*HDIM, bnT + l*HDIM, h, hb);
  }

  k_pool<<<N_GRAPHS,256,0,stream>>>(h, batch, gp);
  k_heads<<<dim3((N_GRAPHS+GB-1)/GB,NPROPS),128,0,stream>>>(gp, h1W, h1b, h2W, h2b, h3W, h3b, out);
}

// Round 5
// 517.619 us; speedup vs baseline: 2.0264x; 1.0146x over previous
//
#include <hip/hip_runtime.h>

#define N_NODES 50000
#define N_EDGES 800000
#define N_GRAPHS 1000
#define NODE_DIMC 128
#define HDIM 256
#define NLAYERS 4
#define NPROPS 3
#define BN_EPSF 1e-5f
#define NBLK 196   // ceil(N_NODES/256)
#define GB 8       // graphs per head-block

typedef __attribute__((ext_vector_type(4))) float f32x4;
typedef __attribute__((ext_vector_type(8))) short short8;
typedef __attribute__((ext_vector_type(8))) unsigned short u16x8;

__device__ __forceinline__ float4 ld4(const float* p){ return *reinterpret_cast<const float4*>(p); }
__device__ __forceinline__ void st4(float* p, float4 v){ *reinterpret_cast<float4*>(p) = v; }
__device__ __forceinline__ unsigned short f2bf(float f){
  unsigned u = __float_as_uint(f);
  return (unsigned short)((u + 0x7FFFu + ((u >> 16) & 1u)) >> 16);
}
__device__ __forceinline__ float bf2f(unsigned short s){ return __uint_as_float(((unsigned)s) << 16); }

__device__ __forceinline__ void gl2lds16(const void* g, void* l){
  __builtin_amdgcn_global_load_lds((const __attribute__((address_space(1))) unsigned int*)g,
                                   (__attribute__((address_space(3))) unsigned int*)l, 16, 0, 0);
}

// ---------------- CSR build ----------------
__global__ void k_count(const int* __restrict__ ei, int* __restrict__ cnt){
  int e = blockIdx.x*256 + threadIdx.x;
  if (e < N_EDGES) atomicAdd(&cnt[ei[N_EDGES + e]], 1);
}

__global__ void k_scan1(const int* __restrict__ cnt, int* __restrict__ rowp, int* __restrict__ part){
  __shared__ int s[256];
  int t = threadIdx.x;
  int i = blockIdx.x*256 + t;
  int v = (i < N_NODES) ? cnt[i] : 0;
  s[t] = v;
  __syncthreads();
  #pragma unroll
  for (int off=1; off<256; off<<=1){
    int x = s[t];
    int y = (t >= off) ? s[t-off] : 0;
    __syncthreads();
    s[t] = x + y;
    __syncthreads();
  }
  if (i < N_NODES) rowp[i+1] = s[t];
  if (t == 255) part[blockIdx.x] = s[255];
}

__global__ void k_scan2(int* __restrict__ part){
  __shared__ int s[256];
  int t = threadIdx.x;
  int v = (t < NBLK) ? part[t] : 0;
  s[t] = v;
  __syncthreads();
  #pragma unroll
  for (int off=1; off<256; off<<=1){
    int x = s[t];
    int y = (t >= off) ? s[t-off] : 0;
    __syncthreads();
    s[t] = x + y;
    __syncthreads();
  }
  if (t < NBLK) part[t] = s[t] - v;   // exclusive offsets
}

__global__ void k_scan3(const int* __restrict__ cnt, int* __restrict__ rowp,
                        const int* __restrict__ part, float* __restrict__ dinv,
                        int* __restrict__ fill){
  int i = blockIdx.x*256 + threadIdx.x;
  if (i < N_NODES){
    rowp[i+1] += part[blockIdx.x];
    dinv[i] = rsqrtf(1.0f + (float)cnt[i]);
    fill[i] = 0;
  }
  if (i == 0) rowp[0] = 0;
}

__global__ void k_fill(const int* __restrict__ ei, const int* __restrict__ rowp, int* __restrict__ fill,
                       const float* __restrict__ dinv, int2* __restrict__ csr){
  int e = blockIdx.x*256 + threadIdx.x;
  if (e >= N_EDGES) return;
  int sr = ei[e];
  int ds = ei[N_EDGES + e];
  int pos = rowp[ds] + atomicAdd(&fill[ds], 1);
  csr[pos] = make_int2(sr, __float_as_int(dinv[sr]));
}

// ---------------- fused prep: x->bf16, embWt, gcnWt, BN fold ----------------
#define XCVT_N (N_NODES*NODE_DIMC/4)
#define EMBWT_N (NODE_DIMC*HDIM)
#define GCNWT_N (NLAYERS*HDIM*HDIM)
#define BN_N (NLAYERS*HDIM)
#define PREP_TOTAL (XCVT_N + EMBWT_N + GCNWT_N + BN_N)

__global__ void k_prep(const float* __restrict__ x, unsigned short* __restrict__ xb,
                       const float* __restrict__ embW, unsigned short* __restrict__ embWt,
                       const float* __restrict__ gcnW, unsigned short* __restrict__ gcnWt,
                       const float* __restrict__ gcnb, const float* __restrict__ bng,
                       const float* __restrict__ bnb, const float* __restrict__ bnm,
                       const float* __restrict__ bnv, float* __restrict__ S, float* __restrict__ T){
  int idx = blockIdx.x*256 + threadIdx.x;
  if (idx < XCVT_N){
    float4 v = ld4(x + (size_t)idx*4);
    ushort4 o;
    o.x = f2bf(v.x); o.y = f2bf(v.y); o.z = f2bf(v.z); o.w = f2bf(v.w);
    *reinterpret_cast<ushort4*>(xb + (size_t)idx*4) = o;
    return;
  }
  idx -= XCVT_N;
  if (idx < EMBWT_N){
    int c = idx >> 7, k = idx & 127;
    embWt[idx] = f2bf(embW[(size_t)k*HDIM + c]);
    return;
  }
  idx -= EMBWT_N;
  if (idx < GCNWT_N){
    int l = idx >> 16, rem = idx & 65535;
    int c = rem >> 8, k = rem & 255;
    gcnWt[idx] = f2bf(gcnW[(size_t)l*HDIM*HDIM + (size_t)k*HDIM + c]);
    return;
  }
  idx -= GCNWT_N;
  if (idx < BN_N){
    float s = bng[idx] * rsqrtf(bnv[idx] + BN_EPSF);
    S[idx] = s;
    T[idx] = (gcnb[idx] - bnm[idx]) * s + bnb[idx];
  }
}

// ---------------- bf16 MFMA GEMM: 128x128 tile, BK=64, 4 waves, double-buffered LDS ----------------
// 2-phase pipelined: stage(next) -> vmcnt(8)+barrier -> ds_read+MFMA(cur) -> barrier.
template<int K, bool EMB>
__global__ __launch_bounds__(256) void k_mgemm(const unsigned short* __restrict__ A,
                                               const unsigned short* __restrict__ Wt,
                                               const float* __restrict__ bias,
                                               unsigned short* __restrict__ mout,
                                               float* __restrict__ hf,
                                               unsigned short* __restrict__ hb,
                                               int nrows){
  __shared__ unsigned short As[2][128*64];   // 16KB each, swizzled content
  __shared__ unsigned short Bs[2][128*64];
  const int t = threadIdx.x;
  const int lane = t & 63;
  const int wid = t >> 6;
  const int wm = wid >> 1, wn = wid & 1;
  const int row0 = blockIdx.x * 128;
  const int col0 = blockIdx.y * 128;
  constexpr int NK = K / 64;

  const int scol = 8 * ((lane & 7) ^ (lane >> 3));   // swizzled source col (shorts)
  const int srow = lane >> 3;
  const int rx = (lane & 7) << 3;                    // read-side XOR (shorts)

  f32x4 acc[4][4];
  #pragma unroll
  for (int i=0;i<4;i++)
    #pragma unroll
    for (int j=0;j<4;j++) acc[i][j] = (f32x4){0.f,0.f,0.f,0.f};

  auto stage = [&](int buf, int k0){
    #pragma unroll
    for (int i=0;i<4;i++){
      int chunkid = wid*4 + i;                 // 0..15, 8 rows each
      int r = chunkid*8 + srow;
      gl2lds16(A + (size_t)(row0 + r)*K + k0 + scol, &As[buf][chunkid*512]);
    }
    #pragma unroll
    for (int i=0;i<4;i++){
      int chunkid = wid*4 + i;
      int r = chunkid*8 + srow;
      gl2lds16(Wt + (size_t)(col0 + r)*K + k0 + scol, &Bs[buf][chunkid*512]);
    }
  };

  stage(0, 0);
  int cur = 0;
  #pragma unroll
  for (int tk = 0; tk < NK; ++tk){
    if (tk + 1 < NK){
      stage(cur ^ 1, (tk+1)*64);
      asm volatile("s_waitcnt vmcnt(8)" ::: "memory");
    } else {
      asm volatile("s_waitcnt vmcnt(0)" ::: "memory");
    }
    __builtin_amdgcn_s_barrier();
    #pragma unroll
    for (int kk=0; kk<64; kk+=32){
      const int kofs = kk + (lane >> 4) * 8;
      short8 af[4], bfv[4];
      #pragma unroll
      for (int mi=0;mi<4;mi++){
        int r = wm*64 + mi*16 + (lane & 15);
        af[mi] = *reinterpret_cast<const short8*>(&As[cur][(r*64 + kofs) ^ rx]);
      }
      #pragma unroll
      for (int ni=0;ni<4;ni++){
        int r = wn*64 + ni*16 + (lane & 15);
        bfv[ni] = *reinterpret_cast<const short8*>(&Bs[cur][(r*64 + kofs) ^ rx]);
      }
      #pragma unroll
      for (int mi=0;mi<4;mi++)
        #pragma unroll
        for (int ni=0;ni<4;ni++)
          acc[mi][ni] = __builtin_amdgcn_mfma_f32_16x16x32_bf16(af[mi], bfv[ni], acc[mi][ni], 0, 0, 0);
    }
    __builtin_amdgcn_s_barrier();
    cur ^= 1;
  }

  const int crow = row0 + wm*64;
  const int ccol = col0 + wn*64 + (lane & 15);
  #pragma unroll
  for (int mi=0;mi<4;mi++){
    #pragma unroll
    for (int j=0;j<4;j++){
      int gr = crow + mi*16 + (lane >> 4)*4 + j;
      if (gr < nrows){
        #pragma unroll
        for (int ni=0;ni<4;ni++){
          float v = acc[mi][ni][j];
          int gc = ccol + ni*16;
          if (EMB){
            v = fmaxf(v + bias[gc], 0.f);
            hf[(size_t)gr*HDIM + gc] = v;
            hb[(size_t)gr*HDIM + gc] = f2bf(v);
          } else {
            mout[(size_t)gr*HDIM + gc] = f2bf(v);
          }
        }
      }
    }
  }
}

// ---------------- fused aggregation: half-wave edge split, 4-deep, packed int2 csr ----------------
template<bool WHB>
__global__ __launch_bounds__(256) void k_agg(const unsigned short* __restrict__ m, const int* __restrict__ rowp,
                                             const int2* __restrict__ csr,
                                             const float* __restrict__ S, const float* __restrict__ T,
                                             float* __restrict__ h, unsigned short* __restrict__ hb){
  int node = blockIdx.x*4 + (threadIdx.x >> 6);
  int lane = threadIdx.x & 63;
  int half = lane >> 5;
  int c = (lane & 31) * 8;

  int s = rowp[node], e = rowp[node+1];
  float dn = rsqrtf(1.0f + (float)(e - s));   // deg = 1 + in-degree

  float acc[8];
  const size_t base = (size_t)node*HDIM + c;
  if (half == 0){
    u16x8 ms = *reinterpret_cast<const u16x8*>(m + base);
    #pragma unroll
    for (int j=0;j<8;j++) acc[j] = bf2f(ms[j]) * dn;
  } else {
    #pragma unroll
    for (int j=0;j<8;j++) acc[j] = 0.f;
  }

  int i = s + half;
  for (; i + 6 < e; i += 8){
    int2 e0 = csr[i], e1 = csr[i+2], e2 = csr[i+4], e3 = csr[i+6];
    float w0 = __int_as_float(e0.y), w1 = __int_as_float(e1.y);
    float w2 = __int_as_float(e2.y), w3 = __int_as_float(e3.y);
    u16x8 m0 = *reinterpret_cast<const u16x8*>(m + (size_t)e0.x*HDIM + c);
    u16x8 m1 = *reinterpret_cast<const u16x8*>(m + (size_t)e1.x*HDIM + c);
    u16x8 m2 = *reinterpret_cast<const u16x8*>(m + (size_t)e2.x*HDIM + c);
    u16x8 m3 = *reinterpret_cast<const u16x8*>(m + (size_t)e3.x*HDIM + c);
    #pragma unroll
    for (int j=0;j<8;j++){
      acc[j] += w0*bf2f(m0[j]) + w1*bf2f(m1[j]);
      acc[j] += w2*bf2f(m2[j]) + w3*bf2f(m3[j]);
    }
  }
  if (i + 2 < e){
    int2 e0 = csr[i], e1 = csr[i+2];
    float w0 = __int_as_float(e0.y), w1 = __int_as_float(e1.y);
    u16x8 m0 = *reinterpret_cast<const u16x8*>(m + (size_t)e0.x*HDIM + c);
    u16x8 m1 = *reinterpret_cast<const u16x8*>(m + (size_t)e1.x*HDIM + c);
    #pragma unroll
    for (int j=0;j<8;j++) acc[j] += w0*bf2f(m0[j]) + w1*bf2f(m1[j]);
    i += 4;
  }
  if (i < e){
    int2 e0 = csr[i];
    float w0 = __int_as_float(e0.y);
    u16x8 m0 = *reinterpret_cast<const u16x8*>(m + (size_t)e0.x*HDIM + c);
    #pragma unroll
    for (int j=0;j<8;j++) acc[j] += w0*bf2f(m0[j]);
  }

  #pragma unroll
  for (int j=0;j<8;j++) acc[j] += __shfl_xor(acc[j], 32);

  if (half == 0){
    float4 S0 = ld4(S + c), S1 = ld4(S + c + 4);
    float4 T0 = ld4(T + c), T1 = ld4(T + c + 4);
    float4 h0 = ld4(h + base), h1 = ld4(h + base + 4);
    float o[8];
    float Sv[8] = {S0.x,S0.y,S0.z,S0.w,S1.x,S1.y,S1.z,S1.w};
    float Tv[8] = {T0.x,T0.y,T0.z,T0.w,T1.x,T1.y,T1.z,T1.w};
    float hv[8] = {h0.x,h0.y,h0.z,h0.w,h1.x,h1.y,h1.z,h1.w};
    #pragma unroll
    for (int j=0;j<8;j++) o[j] = fmaxf(acc[j]*dn*Sv[j] + Tv[j], 0.f) + hv[j];
    st4(h + base,     make_float4(o[0],o[1],o[2],o[3]));
    st4(h + base + 4, make_float4(o[4],o[5],o[6],o[7]));
    if (WHB){
      u16x8 ob;
      #pragma unroll
      for (int j=0;j<8;j++) ob[j] = f2bf(o[j]);
      *reinterpret_cast<u16x8*>(hb + base) = ob;
    }
  }
}

// ---------------- global mean pool (batch_idx sorted) ----------------
__device__ __forceinline__ int lbound(const int* __restrict__ a, int n, int key){
  int lo = 0, hi = n;
  while (lo < hi){ int mid = (lo + hi) >> 1; if (a[mid] < key) lo = mid + 1; else hi = mid; }
  return lo;
}

__global__ __launch_bounds__(256) void k_pool(const float* __restrict__ h, const int* __restrict__ batch,
                                              float* __restrict__ g){
  int gi = blockIdx.x;
  int lo = lbound(batch, N_NODES, gi);
  int hi = lbound(batch, N_NODES, gi + 1);
  float sum = 0.f;
  for (int n = lo; n < hi; ++n) sum += h[(size_t)n*HDIM + threadIdx.x];
  float inv = 1.0f / fmaxf((float)(hi - lo), 1.0f);
  g[(size_t)gi*HDIM + threadIdx.x] = sum * inv;
}

// ---------------- fused 3-layer property heads, GB graphs per block ----------------
__global__ __launch_bounds__(128) void k_heads(const float* __restrict__ g,
                                               const float* __restrict__ W1, const float* __restrict__ b1,
                                               const float* __restrict__ W2, const float* __restrict__ b2,
                                               const float* __restrict__ W3, const float* __restrict__ b3,
                                               float* __restrict__ out){
  int g0 = blockIdx.x * GB, p = blockIdx.y;
  __shared__ float gs[GB][HDIM];
  __shared__ float z1[GB][128];
  int t = threadIdx.x;
  #pragma unroll
  for (int gi=0; gi<GB; gi++){
    gs[gi][t]       = g[(size_t)(g0+gi)*HDIM + t];
    gs[gi][t + 128] = g[(size_t)(g0+gi)*HDIM + t + 128];
  }
  __syncthreads();

  const float* w1 = W1 + (size_t)p*HDIM*128;
  float a[GB];
  #pragma unroll
  for (int gi=0; gi<GB; gi++) a[gi] = 0.f;
  for (int i=0;i<HDIM;i++){
    float wv = w1[(size_t)i*128 + t];
    #pragma unroll
    for (int gi=0; gi<GB; gi++) a[gi] += gs[gi][i] * wv;
  }
  float b1v = b1[p*128 + t];
  #pragma unroll
  for (int gi=0; gi<GB; gi++) z1[gi][t] = fmaxf(a[gi] + b1v, 0.f);
  __syncthreads();

  if (t < 64){
    const float* w2 = W2 + (size_t)p*128*64;
    float a2[GB];
    #pragma unroll
    for (int gi=0; gi<GB; gi++) a2[gi] = 0.f;
    for (int i=0;i<128;i++){
      float wv = w2[(size_t)i*64 + t];
      #pragma unroll
      for (int gi=0; gi<GB; gi++) a2[gi] += z1[gi][i] * wv;
    }
    float w3v = W3[p*64 + t];
    float b2v = b2[p*64 + t];
    float b3v = b3[p];
    #pragma unroll
    for (int gi=0; gi<GB; gi++){
      float z2 = fmaxf(a2[gi] + b2v, 0.f);
      float v = z2 * w3v;
      #pragma unroll
      for (int off=32; off>0; off>>=1) v += __shfl_down(v, off, 64);
      if (t == 0) out[(size_t)(g0+gi)*NPROPS + p] = v + b3v;
    }
  }
}

// ---------------- launch ----------------
extern "C" void kernel_launch(void* const* d_in, const int* in_sizes, int n_in,
                              void* d_out, int out_size, void* d_ws, size_t ws_size,
                              hipStream_t stream){
  const float* x     = (const float*)d_in[0];
  const int*   ei    = (const int*)  d_in[1];
  const int*   batch = (const int*)  d_in[2];
  const float* embW  = (const float*)d_in[3];
  const float* embb  = (const float*)d_in[4];
  const float* gcnW  = (const float*)d_in[5];
  const float* gcnb  = (const float*)d_in[6];
  const float* bng   = (const float*)d_in[7];
  const float* bnb   = (const float*)d_in[8];
  const float* bnm   = (const float*)d_in[9];
  const float* bnv   = (const float*)d_in[10];
  const float* h1W   = (const float*)d_in[11];
  const float* h1b   = (const float*)d_in[12];
  const float* h2W   = (const float*)d_in[13];
  const float* h2b   = (const float*)d_in[14];
  const float* h3W   = (const float*)d_in[15];
  const float* h3b   = (const float*)d_in[16];
  float* out = (float*)d_out;

  char* w = (char*)d_ws;
  auto alloc = [&](size_t bytes)->char*{ char* p = w; w += (bytes + 255) & ~(size_t)255; return p; };
  float*          h    = (float*)         alloc((size_t)N_NODES*HDIM*4);
  unsigned short* hb   = (unsigned short*)alloc((size_t)N_NODES*HDIM*2);
  unsigned short* m    = (unsigned short*)alloc((size_t)N_NODES*HDIM*2);
  int*   cnt  = (int*)  alloc((size_t)N_NODES*4);
  int*   fill = (int*)  alloc((size_t)N_NODES*4);
  int*   rowp = (int*)  alloc((size_t)(N_NODES+1)*4);
  float* dinv = (float*)alloc((size_t)N_NODES*4);
  int2*  csr  = (int2*) alloc((size_t)N_EDGES*8);
  int*   part = (int*)  alloc(1024);
  float* gp   = (float*)alloc((size_t)N_GRAPHS*HDIM*4);
  unsigned short* embWt = (unsigned short*)alloc((size_t)NODE_DIMC*HDIM*2);
  unsigned short* gcnWt = (unsigned short*)alloc((size_t)NLAYERS*HDIM*HDIM*2);
  float* bnS  = (float*)alloc((size_t)NLAYERS*HDIM*4);
  float* bnT  = (float*)alloc((size_t)NLAYERS*HDIM*4);

  hipMemsetAsync(cnt, 0, (size_t)N_NODES*4, stream);

  const int EB = (N_EDGES + 255)/256;
  k_count<<<EB,256,0,stream>>>(ei, cnt);
  k_scan1<<<NBLK,256,0,stream>>>(cnt, rowp, part);
  k_scan2<<<1,256,0,stream>>>(part);
  k_scan3<<<NBLK,256,0,stream>>>(cnt, rowp, part, dinv, fill);
  k_fill<<<EB,256,0,stream>>>(ei, rowp, fill, dinv, csr);

  unsigned short* xb = m;
  k_prep<<<(PREP_TOTAL + 255)/256,256,0,stream>>>(x, xb, embW, embWt, gcnW, gcnWt,
                                                  gcnb, bng, bnb, bnm, bnv, bnS, bnT);

  const int RB = (N_NODES + 127)/128;
  k_mgemm<NODE_DIMC, true><<<dim3(RB,2),256,0,stream>>>(xb, embWt, embb, nullptr, h, hb, N_NODES);

  for (int l = 0; l < NLAYERS; ++l){
    k_mgemm<HDIM, false><<<dim3(RB,2),256,0,stream>>>(hb, gcnWt + (size_t)l*HDIM*HDIM, nullptr, m, nullptr, nullptr, N_NODES);
    if (l < NLAYERS-1)
      k_agg<true ><<<(N_NODES+3)/4,256,0,stream>>>(m, rowp, csr, bnS + l*HDIM, bnT + l*HDIM, h, hb);
    else
      k_agg<false><<<(N_NODES+3)/4,256,0,stream>>>(m, rowp, csr, bnS + l*HDIM, bnT + l*HDIM, h, hb);
  }

  k_pool<<<N_GRAPHS,256,0,stream>>>(h, batch, gp);
  k_heads<<<dim3((N_GRAPHS+GB-1)/GB,NPROPS),128,0,stream>>>(gp, h1W, h1b, h2W, h2b, h3W, h3b, out);
}